// Round 15
// baseline (316.217 us; speedup 1.0000x reference)
//
#include <hip/hip_runtime.h>

#define N_NODES 100000
#define N_EDGES 1600000
#define N_LABEL 200000
#define C_IN 128
#define C_HID 256
#define C_OUT 128

#define BCHUNK 64                                 // nodes per bucket
#define NBUCK ((N_NODES + BCHUNK - 1) / BCHUNK)   // 1563
#define NBF 64                                    // multisplit blocks
#define EPB (N_EDGES / NBF)                       // 25000 edges per block
#define FLEN (NBUCK * NBF)                        // 100032
#define ESTORE 2048                               // max edges per bucket
#define CAST_NB ((N_NODES * C_IN) / (256 * 8))    // 6250
#define SBLK ((FLEN + 1023) / 1024)               // 98

typedef __attribute__((ext_vector_type(8))) short bf16x8;
typedef __attribute__((ext_vector_type(4))) float f32x4;

__device__ __forceinline__ ushort f2bf(float f) {  // RTNE
  uint u = __float_as_uint(f);
  return (ushort)((u + 0x7fffu + ((u >> 16) & 1u)) >> 16);
}

__device__ __forceinline__ uint pack2(float lo, float hi) {
  return (uint)f2bf(lo) | ((uint)f2bf(hi) << 16);
}

__device__ __forceinline__ float bfl(uint u) { return __uint_as_float(u << 16); }
__device__ __forceinline__ float bfh(uint u) {
  return __uint_as_float(u & 0xffff0000u);
}

__device__ __forceinline__ void async_copy16(const void* g, void* lds) {
  __builtin_amdgcn_global_load_lds((const __attribute__((address_space(1))) void*)g,
                                   (__attribute__((address_space(3))) void*)lds,
                                   16, 0, 0);
}

// ---------------------------------------------------------------------------
// Fused prep: blocks [0,64) = bucket histogram; [64,320) = weight transpose;
// [320, 320+6250) = x -> bf16 cast.
// ---------------------------------------------------------------------------
__global__ __launch_bounds__(256) void prep_kernel(const int* __restrict__ dst,
                                                   int* __restrict__ cnt,
                                                   const float* __restrict__ Wl1,
                                                   const float* __restrict__ Wr1,
                                                   const float* __restrict__ Wl2,
                                                   const float* __restrict__ Wr2,
                                                   ushort* __restrict__ WT1,
                                                   ushort* __restrict__ WT2,
                                                   const float* __restrict__ x,
                                                   ushort* __restrict__ xb) {
  __shared__ int lcnt[NBUCK];
  const int blk = blockIdx.x;
  const int t = threadIdx.x;
  if (blk < NBF) {  // --- bucket_count ---
    const int base = blk * EPB;
    for (int b = t; b < NBUCK; b += 256) lcnt[b] = 0;
    __syncthreads();
    for (int i = t; i < EPB; i += 256) {
      atomicAdd(&lcnt[dst[base + i] >> 6], 1);
    }
    __syncthreads();
    for (int b = t; b < NBUCK; b += 256) cnt[b * NBF + blk] = lcnt[b];
  } else if (blk < NBF + 256) {  // --- prep_wt ---
    const int n = blk - NBF;
    const int k = t;
    const float v1 = (k < 128) ? Wl1[k * 256 + n] : Wr1[(k - 128) * 256 + n];
    WT1[n * 256 + k] = f2bf(v1);
    const float v2 = (n < 128) ? Wl2[k * 128 + n] : Wr2[k * 128 + (n - 128)];
    WT2[n * 256 + k] = f2bf(v2);
  } else {  // --- cast_bf16 ---
    const size_t i = ((size_t)(blk - NBF - 256) * 256 + t) * 8;
    const float4 a = *(const float4*)&x[i];
    const float4 b = *(const float4*)&x[i + 4];
    uint4 o;
    o.x = pack2(a.x, a.y);
    o.y = pack2(a.z, a.w);
    o.z = pack2(b.x, b.y);
    o.w = pack2(b.z, b.w);
    *(uint4*)&xb[i] = o;
  }
}

// ---------------------------------------------------------------------------
// Scan phase 1: per-block sums of cnt (1024 elems / block).
// ---------------------------------------------------------------------------
__global__ __launch_bounds__(256) void scan_sums(const int* __restrict__ a,
                                                 int* __restrict__ bsum) {
  __shared__ int red[256];
  const int t = threadIdx.x;
  const int idx = blockIdx.x * 1024 + t * 4;
  int s = 0;
  if (idx + 3 < FLEN) {
    const int4 v = *(const int4*)&a[idx];
    s = v.x + v.y + v.z + v.w;
  } else {
    for (int j = 0; j < 4 && idx + j < FLEN; ++j) s += a[idx + j];
  }
  red[t] = s;
  __syncthreads();
  for (int off = 128; off > 0; off >>= 1) {
    if (t < off) red[t] += red[t + off];
    __syncthreads();
  }
  if (t == 0) bsum[blockIdx.x] = red[0];
}

// ---------------------------------------------------------------------------
// Scan phase 2 (fused tops): each block redundantly scans the 98 block sums.
// ---------------------------------------------------------------------------
__global__ __launch_bounds__(256) void scan_apply(int* __restrict__ a,
                                                  const int* __restrict__ bsum) {
  __shared__ int sh[256];
  __shared__ int bsc[128];
  const int t = threadIdx.x;
  if (t < 128) bsc[t] = (t < SBLK) ? bsum[t] : 0;
  __syncthreads();
  for (int off = 1; off < 128; off <<= 1) {
    int v = 0;
    if (t < 128 && t >= off) v = bsc[t - off];
    __syncthreads();
    if (t < 128 && t >= off) bsc[t] += v;
    __syncthreads();
  }
  const int bbase = (blockIdx.x == 0) ? 0 : bsc[blockIdx.x - 1];
  if (blockIdx.x == SBLK - 1 && t == 0) a[FLEN] = bsc[SBLK - 1];

  const int idx = blockIdx.x * 1024 + t * 4;
  int4 v = make_int4(0, 0, 0, 0);
  const bool full = (idx + 3 < FLEN);
  if (full) {
    v = *(const int4*)&a[idx];
  } else {
    if (idx + 0 < FLEN) v.x = a[idx + 0];
    if (idx + 1 < FLEN) v.y = a[idx + 1];
    if (idx + 2 < FLEN) v.z = a[idx + 2];
    if (idx + 3 < FLEN) v.w = a[idx + 3];
  }
  sh[t] = v.x + v.y + v.z + v.w;
  __syncthreads();
  for (int off = 1; off < 256; off <<= 1) {
    int u = 0;
    if (t >= off) u = sh[t - off];
    __syncthreads();
    if (t >= off) sh[t] += u;
    __syncthreads();
  }
  const int base = bbase + ((t == 0) ? 0 : sh[t - 1]);
  int4 e;
  e.x = base;
  e.y = base + v.x;
  e.z = base + v.x + v.y;
  e.w = base + v.x + v.y + v.z;
  if (full) {
    *(int4*)&a[idx] = e;
  } else {
    if (idx + 0 < FLEN) a[idx + 0] = e.x;
    if (idx + 1 < FLEN) a[idx + 1] = e.y;
    if (idx + 2 < FLEN) a[idx + 2] = e.z;
    if (idx + 3 < FLEN) a[idx + 3] = e.w;
  }
}

// ---------------------------------------------------------------------------
// Multisplit P3: deterministic bucket scatter with LDS cursors.
// ---------------------------------------------------------------------------
__global__ __launch_bounds__(256) void bucket_fill(const int* __restrict__ src,
                                                   const int* __restrict__ dst,
                                                   const int* __restrict__ cnt,
                                                   uint* __restrict__ tmp) {
  __shared__ int lcur[NBUCK];
  const int t = threadIdx.x;
  const int base = blockIdx.x * EPB;
  for (int b = t; b < NBUCK; b += 256) lcur[b] = cnt[b * NBF + blockIdx.x];
  __syncthreads();
  for (int i = t; i < EPB; i += 256) {
    const int d = dst[base + i];
    const int s = src[base + i];
    const int pos = atomicAdd(&lcur[d >> 6], 1);
    tmp[pos] = ((uint)s << 6) | (uint)(d & 63);
  }
}

// ---------------------------------------------------------------------------
// Per-bucket CSR finalize, in LDS; tmp becomes csr_src in place.
// ---------------------------------------------------------------------------
__global__ __launch_bounds__(256) void csr_build(const int* __restrict__ cnt,
                                                 uint* __restrict__ tmp,
                                                 int* __restrict__ row_start) {
  __shared__ uint est[ESTORE];
  __shared__ uint eso[ESTORE];
  __shared__ int lcnt[BCHUNK];
  __shared__ int lcur[BCHUNK];
  const int b = blockIdx.x;
  const int t = threadIdx.x;
  const int s = cnt[b * NBF];
  const int e = cnt[(b + 1) * NBF];
  const int n = e - s;
  for (int j = t; j < n; j += 256) est[j] = tmp[s + j];
  if (t < BCHUNK) lcnt[t] = 0;
  __syncthreads();
  for (int j = t; j < n; j += 256) atomicAdd(&lcnt[est[j] & 63], 1);
  __syncthreads();
  for (int off = 1; off < BCHUNK; off <<= 1) {
    int v = 0;
    if (t >= off && t < BCHUNK) v = lcnt[t - off];
    __syncthreads();
    if (t >= off && t < BCHUNK) lcnt[t] += v;
    __syncthreads();
  }
  if (t < BCHUNK) {
    const int ex = (t == 0) ? 0 : lcnt[t - 1];
    lcur[t] = ex;
    const int node = b * BCHUNK + t;
    if (node < N_NODES) row_start[node] = s + ex;
  }
  if (b == NBUCK - 1 && t == 0) row_start[N_NODES] = e;
  __syncthreads();
  for (int j = t; j < n; j += 256) {
    const uint v = est[j];
    const int pos = atomicAdd(&lcur[v & 63], 1);
    eso[pos] = v >> 6;
  }
  __syncthreads();
  for (int j = t; j < n; j += 256) tmp[s + j] = eso[j];
}

// ---------------------------------------------------------------------------
// Mean aggregation: one wave per node; 4 edge-slots x 16 lanes x 16B.
// MODE 0: write bf16 mean.  MODE 1: zb[node] += mean (bf16 RMW, slot 0).
// ---------------------------------------------------------------------------
template <int MODE>
__global__ __launch_bounds__(256) void gather_mean_b(const int* __restrict__ row_start,
                                                     const uint* __restrict__ csr_src,
                                                     const ushort* __restrict__ feat,
                                                     ushort* __restrict__ bout,
                                                     ushort* __restrict__ zb) {
  const int wid = blockIdx.x * 4 + (threadIdx.x >> 6);
  const int lane = threadIdx.x & 63;
  if (wid >= N_NODES) return;
  const int s = row_start[wid];
  const int e = row_start[wid + 1];
  const int slot = lane >> 4;
  const int c0 = (lane & 15) * 8;
  float acc[8] = {};
  int j = s + slot;
#define ACC8(r)                                   \
  acc[0] += bfl(r.x); acc[1] += bfh(r.x);         \
  acc[2] += bfl(r.y); acc[3] += bfh(r.y);         \
  acc[4] += bfl(r.z); acc[5] += bfh(r.z);         \
  acc[6] += bfl(r.w); acc[7] += bfh(r.w);
  for (; j + 12 < e; j += 16) {
    const uint s0 = csr_src[j];
    const uint s1 = csr_src[j + 4];
    const uint s2 = csr_src[j + 8];
    const uint s3 = csr_src[j + 12];
    const uint4 r0 = *(const uint4*)&feat[(size_t)s0 * 128 + c0];
    const uint4 r1 = *(const uint4*)&feat[(size_t)s1 * 128 + c0];
    const uint4 r2 = *(const uint4*)&feat[(size_t)s2 * 128 + c0];
    const uint4 r3 = *(const uint4*)&feat[(size_t)s3 * 128 + c0];
    ACC8(r0) ACC8(r1) ACC8(r2) ACC8(r3)
  }
  for (; j < e; j += 4) {
    const uint s0 = csr_src[j];
    const uint4 r0 = *(const uint4*)&feat[(size_t)s0 * 128 + c0];
    ACC8(r0)
  }
#undef ACC8
#pragma unroll
  for (int k = 0; k < 8; ++k) {
    acc[k] += __shfl_xor(acc[k], 16, 64);
    acc[k] += __shfl_xor(acc[k], 32, 64);
  }
  if (slot == 0) {
    const float rd = 1.0f / fmaxf((float)(e - s), 1.0f);
    if (MODE == 0) {
      uint4 o;
      o.x = pack2(acc[0] * rd, acc[1] * rd);
      o.y = pack2(acc[2] * rd, acc[3] * rd);
      o.z = pack2(acc[4] * rd, acc[5] * rd);
      o.w = pack2(acc[6] * rd, acc[7] * rd);
      *(uint4*)&bout[(size_t)wid * 128 + c0] = o;
    } else {
      uint4 zv = *(const uint4*)&zb[(size_t)wid * 128 + c0];
      uint4 o;
      o.x = pack2(bfl(zv.x) + acc[0] * rd, bfh(zv.x) + acc[1] * rd);
      o.y = pack2(bfl(zv.y) + acc[2] * rd, bfh(zv.y) + acc[3] * rd);
      o.z = pack2(bfl(zv.z) + acc[4] * rd, bfh(zv.z) + acc[5] * rd);
      o.w = pack2(bfl(zv.w) + acc[6] * rd, bfh(zv.w) + acc[7] * rd);
      *(uint4*)&zb[(size_t)wid * 128 + c0] = o;
    }
  }
}

// ---------------------------------------------------------------------------
// Fused MLP chain, 3-barrier structure:
//   stage full A tile (64 rows x [aggb|xb] = 32KB, swizzled src) -> barrier
//   phase 1 k-loop, NO barriers: A-frags from LDS, B-frags DIRECT from WT1
//     (128KB, L2-resident; per-wave reads are full 64B lines)
//   barrier (A dead) -> epilogue writes Ht into the SAME 32KB buffer -> barrier
//   phase 2: A-frags from Ht (LDS), B-frags direct from WT2
// LDS = 32KB -> 4-5 blocks/CU (~50-60% occupancy vs R14's 24%).
// Swizzle (rule #21): LDS[r][cb] = G[r][cb ^ ((r&7)<<4)]; reads XOR same.
// ---------------------------------------------------------------------------
__global__ __launch_bounds__(256) void gemm_fused(const ushort* __restrict__ aggb,
                                                  const ushort* __restrict__ xb,
                                                  const ushort* __restrict__ WT1,
                                                  const ushort* __restrict__ WT2,
                                                  const float* __restrict__ bl1,
                                                  const float* __restrict__ bl2,
                                                  ushort* __restrict__ p,
                                                  ushort* __restrict__ zb) {
  __shared__ ushort AH[64 * 256];   // 32 KB: A-tile (phase 1), then Ht (phase 2)
  const int tid = threadIdx.x;
  const int w = tid >> 6;
  const int l = tid & 63;
  const int row0 = blockIdx.x * 64;
  const int wn = w * 64;
  const int fr = l & 15;
  const int kg16 = (l >> 4) * 16;   // byte offset of lane's 16B k-chunk
  const int cr = (l >> 4) * 4;
  const int cc = l & 15;

  // ---- stage full A tile: row r = [aggb[node] (256B) | xb[node] (256B)] ----
  // flat LDS byte = it*4096 + w*1024 + l*16 -> row = it*8 + w*2 + (l>>5),
  // chunk cb = (l&31)*16. Source pre-swizzled: G-chunk = cb ^ ((r&7)<<4)
  // (XOR touches bits 4-6 only, never crosses the 256B aggb/xb boundary).
#pragma unroll
  for (int it = 0; it < 8; ++it) {
    const int r = it * 8 + w * 2 + (l >> 5);
    const int cb = (l & 31) * 16;
    const int cbs = cb ^ ((r & 7) << 4);
    int node = row0 + r;
    node = (node < N_NODES) ? node : (N_NODES - 1);
    const char* src = (cbs < 256)
        ? (const char*)aggb + (size_t)node * 256 + cbs
        : (const char*)xb + (size_t)node * 256 + (cbs - 256);
    async_copy16(src, (char*)AH + it * 4096 + w * 1024);
  }
  __syncthreads();

  // ---- phase 1: acc = [aggb|xb] @ WT1, no barriers in k-loop ----
  f32x4 acc[4][4] = {};
#pragma unroll
  for (int kc = 0; kc < 8; ++kc) {
    bf16x8 af[4], bfr[4];
#pragma unroll
    for (int i = 0; i < 4; ++i) {
      const int ra = i * 16 + fr;
      const int ba = ra * 512 + ((kc * 64 + kg16) ^ ((ra & 7) << 4));
      af[i] = *(const bf16x8*)((const char*)AH + ba);
    }
#pragma unroll
    for (int j = 0; j < 4; ++j) {
      const int n = wn + j * 16 + fr;
      bfr[j] = *(const bf16x8*)((const char*)WT1 + (size_t)n * 512 + kc * 64 +
                                kg16);
    }
#pragma unroll
    for (int i = 0; i < 4; ++i)
#pragma unroll
      for (int j = 0; j < 4; ++j)
        acc[i][j] = __builtin_amdgcn_mfma_f32_16x16x32_bf16(af[i], bfr[j],
                                                            acc[i][j], 0, 0, 0);
  }
  __syncthreads();  // A-tile dead; buffer becomes Ht

  // ---- epilogue 1: bias + relu -> Ht (same buffer, same swizzle) ----
#pragma unroll
  for (int i = 0; i < 4; ++i) {
#pragma unroll
    for (int j = 0; j < 4; ++j) {
      const int col = wn + j * 16 + cc;
      const float bv = bl1[col];
#pragma unroll
      for (int r = 0; r < 4; ++r) {
        const int row = i * 16 + cr + r;
        const float v = fmaxf(acc[i][j][r] + bv, 0.f);
        const int ba = row * 512 + ((col * 2) ^ ((row & 7) << 4));
        *(ushort*)((char*)AH + ba) = f2bf(v);
      }
    }
  }
  __syncthreads();

  // ---- phase 2: [p | zb] = Ht @ WT2 ----
  f32x4 acc2[4][4] = {};
#pragma unroll
  for (int kc = 0; kc < 8; ++kc) {
    bf16x8 af[4], bfr[4];
#pragma unroll
    for (int i = 0; i < 4; ++i) {
      const int row = i * 16 + fr;
      const int ba = row * 512 + ((kc * 64 + kg16) ^ ((row & 7) << 4));
      af[i] = *(const bf16x8*)((const char*)AH + ba);
    }
#pragma unroll
    for (int j = 0; j < 4; ++j) {
      const int n = wn + j * 16 + fr;
      bfr[j] = *(const bf16x8*)((const char*)WT2 + (size_t)n * 512 + kc * 64 +
                                kg16);
    }
#pragma unroll
    for (int i = 0; i < 4; ++i)
#pragma unroll
      for (int j = 0; j < 4; ++j)
        acc2[i][j] = __builtin_amdgcn_mfma_f32_16x16x32_bf16(af[i], bfr[j],
                                                             acc2[i][j], 0, 0, 0);
  }
#pragma unroll
  for (int i = 0; i < 4; ++i) {
#pragma unroll
    for (int j = 0; j < 4; ++j) {
      const int col = wn + j * 16 + cc;  // <128 -> p, >=128 -> zb
      const int gcl = col & 127;
      const bool is_p = (col < 128);
      const float bv = is_p ? 0.f : bl2[gcl];
      ushort* dst = is_p ? p : zb;
#pragma unroll
      for (int r = 0; r < 4; ++r) {
        const int grow = row0 + i * 16 + cr + r;
        if (grow < N_NODES) {
          dst[(size_t)grow * 128 + gcl] = f2bf(acc2[i][j][r] + bv);
        }
      }
    }
  }
}

// ---------------------------------------------------------------------------
// Decode: 16 lanes/edge x 16B (8 bf16); 4 edge-slots per wave.
// ---------------------------------------------------------------------------
__global__ __launch_bounds__(256) void dot_kernel(const int* __restrict__ ls,
                                                  const int* __restrict__ ld,
                                                  const ushort* __restrict__ zb,
                                                  float* __restrict__ out) {
  long long tid = (long long)blockIdx.x * 256 + threadIdx.x;
  int e = (int)(tid >> 4);
  int lane = (int)(tid & 15);
  if (e >= N_LABEL) return;
  int a = ls[e], b = ld[e];
  const uint4 va = *(const uint4*)&zb[(size_t)a * 128 + lane * 8];
  const uint4 vb = *(const uint4*)&zb[(size_t)b * 128 + lane * 8];
  float s = bfl(va.x) * bfl(vb.x) + bfh(va.x) * bfh(vb.x) +
            bfl(va.y) * bfl(vb.y) + bfh(va.y) * bfh(vb.y) +
            bfl(va.z) * bfl(vb.z) + bfh(va.z) * bfh(vb.z) +
            bfl(va.w) * bfl(vb.w) + bfh(va.w) * bfh(vb.w);
  s += __shfl_xor(s, 1, 16);
  s += __shfl_xor(s, 2, 16);
  s += __shfl_xor(s, 4, 16);
  s += __shfl_xor(s, 8, 16);
  if (lane == 0) out[e] = s;
}

extern "C" void kernel_launch(void* const* d_in, const int* in_sizes, int n_in,
                              void* d_out, int out_size, void* d_ws, size_t ws_size,
                              hipStream_t stream) {
  const float* x = (const float*)d_in[0];
  const int* ei = (const int*)d_in[1];
  const int* eli = (const int*)d_in[2];
  const float* Wl1 = (const float*)d_in[3];
  const float* bl1 = (const float*)d_in[4];
  const float* Wr1 = (const float*)d_in[5];
  const float* Wl2 = (const float*)d_in[6];
  const float* bl2 = (const float*)d_in[7];
  const float* Wr2 = (const float*)d_in[8];
  float* out = (float*)d_out;

  const int* e_src = ei;
  const int* e_dst = ei + N_EDGES;
  const int* l_src = eli;
  const int* l_dst = eli + N_LABEL;

  char* ws = (char*)d_ws;
  ushort* xb = (ushort*)(ws + 0);           //  25.6 MB
  ushort* aggb = (ushort*)(ws + 25600000);  //  25.6 MB
  ushort* p = (ushort*)(ws + 102400000);    //  25.6 MB
  ushort* zb = (ushort*)(ws + 128000000);   //  25.6 MB (bf16 z)
  ushort* WT1 = (ushort*)(ws + 179200000);  // 128 KB
  ushort* WT2 = (ushort*)(ws + 179331072);  // 128 KB
  uint* tmp = (uint*)(ws + 179462144);      // 6.4 MB packed edges -> csr_src
  int* cnt = (int*)(ws + 185862144);        // (FLEN+1) ints
  int* bsum = (int*)(ws + 186270000);       // 128 ints
  int* row_start = (int*)(ws + 186280000);  // (N_NODES+1) ints

  // --- fused prep: bucket histogram + weight transpose + x cast ---
  prep_kernel<<<NBF + 256 + CAST_NB, 256, 0, stream>>>(
      e_dst, cnt, Wl1, Wr1, Wl2, Wr2, WT1, WT2, x, xb);
  // --- scan of cnt ---
  scan_sums<<<SBLK, 256, 0, stream>>>(cnt, bsum);
  scan_apply<<<SBLK, 256, 0, stream>>>(cnt, bsum);
  // --- deterministic bucket scatter + per-bucket CSR finalize ---
  bucket_fill<<<NBF, 256, 0, stream>>>(e_src, e_dst, cnt, tmp);
  csr_build<<<NBUCK, 256, 0, stream>>>(cnt, tmp, row_start);

  // --- layer 1 aggregation ---
  gather_mean_b<0><<<(N_NODES + 3) / 4, 256, 0, stream>>>(row_start, tmp, xb,
                                                          aggb, nullptr);
  // --- fused MLP chain: h (LDS-only) -> p, zb ---
  gemm_fused<<<(N_NODES + 63) / 64, 256, 0, stream>>>(aggb, xb, WT1, WT2, bl1,
                                                      bl2, p, zb);
  // --- layer 2 aggregation: zb += mean(p[neighbors]) ---
  gather_mean_b<1><<<(N_NODES + 3) / 4, 256, 0, stream>>>(row_start, tmp, p,
                                                          nullptr, zb);

  // --- decode ---
  dot_kernel<<<(int)(((long long)N_LABEL * 16 + 255) / 256), 256, 0, stream>>>(
      l_src, l_dst, zb, out);
}

// Round 16
// 305.101 us; speedup vs baseline: 1.0364x; 1.0364x over previous
//
#include <hip/hip_runtime.h>

#define N_NODES 100000
#define N_EDGES 1600000
#define N_LABEL 200000
#define C_IN 128
#define C_HID 256
#define C_OUT 128

#define BCHUNK 64                                 // nodes per bucket
#define NBUCK ((N_NODES + BCHUNK - 1) / BCHUNK)   // 1563
#define NBF 64                                    // multisplit blocks
#define EPB (N_EDGES / NBF)                       // 25000 edges per block
#define FLEN (NBUCK * NBF)                        // 100032
#define ESTORE 2048                               // max edges per bucket
#define CAST_NB ((N_NODES * C_IN) / (256 * 8))    // 6250
#define SBLK ((FLEN + 1023) / 1024)               // 98

typedef __attribute__((ext_vector_type(8))) short bf16x8;
typedef __attribute__((ext_vector_type(4))) float f32x4;

__device__ __forceinline__ ushort f2bf(float f) {  // RTNE
  uint u = __float_as_uint(f);
  return (ushort)((u + 0x7fffu + ((u >> 16) & 1u)) >> 16);
}

__device__ __forceinline__ uint pack2(float lo, float hi) {
  return (uint)f2bf(lo) | ((uint)f2bf(hi) << 16);
}

__device__ __forceinline__ float bfl(uint u) { return __uint_as_float(u << 16); }
__device__ __forceinline__ float bfh(uint u) {
  return __uint_as_float(u & 0xffff0000u);
}

__device__ __forceinline__ void async_copy16(const void* g, void* lds) {
  __builtin_amdgcn_global_load_lds((const __attribute__((address_space(1))) void*)g,
                                   (__attribute__((address_space(3))) void*)lds,
                                   16, 0, 0);
}

// ---------------------------------------------------------------------------
// Fused prep: blocks [0,64) = bucket histogram; [64,320) = weight transpose;
// [320, 320+6250) = x -> bf16 cast.
// ---------------------------------------------------------------------------
__global__ __launch_bounds__(256) void prep_kernel(const int* __restrict__ dst,
                                                   int* __restrict__ cnt,
                                                   const float* __restrict__ Wl1,
                                                   const float* __restrict__ Wr1,
                                                   const float* __restrict__ Wl2,
                                                   const float* __restrict__ Wr2,
                                                   ushort* __restrict__ WT1,
                                                   ushort* __restrict__ WT2,
                                                   const float* __restrict__ x,
                                                   ushort* __restrict__ xb) {
  __shared__ int lcnt[NBUCK];
  const int blk = blockIdx.x;
  const int t = threadIdx.x;
  if (blk < NBF) {  // --- bucket_count ---
    const int base = blk * EPB;
    for (int b = t; b < NBUCK; b += 256) lcnt[b] = 0;
    __syncthreads();
    for (int i = t; i < EPB; i += 256) {
      atomicAdd(&lcnt[dst[base + i] >> 6], 1);
    }
    __syncthreads();
    for (int b = t; b < NBUCK; b += 256) cnt[b * NBF + blk] = lcnt[b];
  } else if (blk < NBF + 256) {  // --- prep_wt ---
    const int n = blk - NBF;
    const int k = t;
    const float v1 = (k < 128) ? Wl1[k * 256 + n] : Wr1[(k - 128) * 256 + n];
    WT1[n * 256 + k] = f2bf(v1);
    const float v2 = (n < 128) ? Wl2[k * 128 + n] : Wr2[k * 128 + (n - 128)];
    WT2[n * 256 + k] = f2bf(v2);
  } else {  // --- cast_bf16 ---
    const size_t i = ((size_t)(blk - NBF - 256) * 256 + t) * 8;
    const float4 a = *(const float4*)&x[i];
    const float4 b = *(const float4*)&x[i + 4];
    uint4 o;
    o.x = pack2(a.x, a.y);
    o.y = pack2(a.z, a.w);
    o.z = pack2(b.x, b.y);
    o.w = pack2(b.z, b.w);
    *(uint4*)&xb[i] = o;
  }
}

// ---------------------------------------------------------------------------
// Scan phase 1: per-block sums of cnt (1024 elems / block).
// ---------------------------------------------------------------------------
__global__ __launch_bounds__(256) void scan_sums(const int* __restrict__ a,
                                                 int* __restrict__ bsum) {
  __shared__ int red[256];
  const int t = threadIdx.x;
  const int idx = blockIdx.x * 1024 + t * 4;
  int s = 0;
  if (idx + 3 < FLEN) {
    const int4 v = *(const int4*)&a[idx];
    s = v.x + v.y + v.z + v.w;
  } else {
    for (int j = 0; j < 4 && idx + j < FLEN; ++j) s += a[idx + j];
  }
  red[t] = s;
  __syncthreads();
  for (int off = 128; off > 0; off >>= 1) {
    if (t < off) red[t] += red[t + off];
    __syncthreads();
  }
  if (t == 0) bsum[blockIdx.x] = red[0];
}

// ---------------------------------------------------------------------------
// Scan phase 2 (fused tops): each block redundantly scans the 98 block sums.
// ---------------------------------------------------------------------------
__global__ __launch_bounds__(256) void scan_apply(int* __restrict__ a,
                                                  const int* __restrict__ bsum) {
  __shared__ int sh[256];
  __shared__ int bsc[128];
  const int t = threadIdx.x;
  if (t < 128) bsc[t] = (t < SBLK) ? bsum[t] : 0;
  __syncthreads();
  for (int off = 1; off < 128; off <<= 1) {
    int v = 0;
    if (t < 128 && t >= off) v = bsc[t - off];
    __syncthreads();
    if (t < 128 && t >= off) bsc[t] += v;
    __syncthreads();
  }
  const int bbase = (blockIdx.x == 0) ? 0 : bsc[blockIdx.x - 1];
  if (blockIdx.x == SBLK - 1 && t == 0) a[FLEN] = bsc[SBLK - 1];

  const int idx = blockIdx.x * 1024 + t * 4;
  int4 v = make_int4(0, 0, 0, 0);
  const bool full = (idx + 3 < FLEN);
  if (full) {
    v = *(const int4*)&a[idx];
  } else {
    if (idx + 0 < FLEN) v.x = a[idx + 0];
    if (idx + 1 < FLEN) v.y = a[idx + 1];
    if (idx + 2 < FLEN) v.z = a[idx + 2];
    if (idx + 3 < FLEN) v.w = a[idx + 3];
  }
  sh[t] = v.x + v.y + v.z + v.w;
  __syncthreads();
  for (int off = 1; off < 256; off <<= 1) {
    int u = 0;
    if (t >= off) u = sh[t - off];
    __syncthreads();
    if (t >= off) sh[t] += u;
    __syncthreads();
  }
  const int base = bbase + ((t == 0) ? 0 : sh[t - 1]);
  int4 e;
  e.x = base;
  e.y = base + v.x;
  e.z = base + v.x + v.y;
  e.w = base + v.x + v.y + v.z;
  if (full) {
    *(int4*)&a[idx] = e;
  } else {
    if (idx + 0 < FLEN) a[idx + 0] = e.x;
    if (idx + 1 < FLEN) a[idx + 1] = e.y;
    if (idx + 2 < FLEN) a[idx + 2] = e.z;
    if (idx + 3 < FLEN) a[idx + 3] = e.w;
  }
}

// ---------------------------------------------------------------------------
// Multisplit P3: deterministic bucket scatter with LDS cursors.
// ---------------------------------------------------------------------------
__global__ __launch_bounds__(256) void bucket_fill(const int* __restrict__ src,
                                                   const int* __restrict__ dst,
                                                   const int* __restrict__ cnt,
                                                   uint* __restrict__ tmp) {
  __shared__ int lcur[NBUCK];
  const int t = threadIdx.x;
  const int base = blockIdx.x * EPB;
  for (int b = t; b < NBUCK; b += 256) lcur[b] = cnt[b * NBF + blockIdx.x];
  __syncthreads();
  for (int i = t; i < EPB; i += 256) {
    const int d = dst[base + i];
    const int s = src[base + i];
    const int pos = atomicAdd(&lcur[d >> 6], 1);
    tmp[pos] = ((uint)s << 6) | (uint)(d & 63);
  }
}

// ---------------------------------------------------------------------------
// Per-bucket CSR finalize, in LDS; tmp becomes csr_src in place.
// ---------------------------------------------------------------------------
__global__ __launch_bounds__(256) void csr_build(const int* __restrict__ cnt,
                                                 uint* __restrict__ tmp,
                                                 int* __restrict__ row_start) {
  __shared__ uint est[ESTORE];
  __shared__ uint eso[ESTORE];
  __shared__ int lcnt[BCHUNK];
  __shared__ int lcur[BCHUNK];
  const int b = blockIdx.x;
  const int t = threadIdx.x;
  const int s = cnt[b * NBF];
  const int e = cnt[(b + 1) * NBF];
  const int n = e - s;
  for (int j = t; j < n; j += 256) est[j] = tmp[s + j];
  if (t < BCHUNK) lcnt[t] = 0;
  __syncthreads();
  for (int j = t; j < n; j += 256) atomicAdd(&lcnt[est[j] & 63], 1);
  __syncthreads();
  for (int off = 1; off < BCHUNK; off <<= 1) {
    int v = 0;
    if (t >= off && t < BCHUNK) v = lcnt[t - off];
    __syncthreads();
    if (t >= off && t < BCHUNK) lcnt[t] += v;
    __syncthreads();
  }
  if (t < BCHUNK) {
    const int ex = (t == 0) ? 0 : lcnt[t - 1];
    lcur[t] = ex;
    const int node = b * BCHUNK + t;
    if (node < N_NODES) row_start[node] = s + ex;
  }
  if (b == NBUCK - 1 && t == 0) row_start[N_NODES] = e;
  __syncthreads();
  for (int j = t; j < n; j += 256) {
    const uint v = est[j];
    const int pos = atomicAdd(&lcur[v & 63], 1);
    eso[pos] = v >> 6;
  }
  __syncthreads();
  for (int j = t; j < n; j += 256) tmp[s + j] = eso[j];
}

// ---------------------------------------------------------------------------
// Mean aggregation: one wave per node; 4 edge-slots x 16 lanes x 16B.
// MODE 0: write bf16 mean.  MODE 1: zb[node] += mean (bf16 RMW, slot 0).
// ---------------------------------------------------------------------------
template <int MODE>
__global__ __launch_bounds__(256) void gather_mean_b(const int* __restrict__ row_start,
                                                     const uint* __restrict__ csr_src,
                                                     const ushort* __restrict__ feat,
                                                     ushort* __restrict__ bout,
                                                     ushort* __restrict__ zb) {
  const int wid = blockIdx.x * 4 + (threadIdx.x >> 6);
  const int lane = threadIdx.x & 63;
  if (wid >= N_NODES) return;
  const int s = row_start[wid];
  const int e = row_start[wid + 1];
  const int slot = lane >> 4;
  const int c0 = (lane & 15) * 8;
  float acc[8] = {};
  int j = s + slot;
#define ACC8(r)                                   \
  acc[0] += bfl(r.x); acc[1] += bfh(r.x);         \
  acc[2] += bfl(r.y); acc[3] += bfh(r.y);         \
  acc[4] += bfl(r.z); acc[5] += bfh(r.z);         \
  acc[6] += bfl(r.w); acc[7] += bfh(r.w);
  for (; j + 12 < e; j += 16) {
    const uint s0 = csr_src[j];
    const uint s1 = csr_src[j + 4];
    const uint s2 = csr_src[j + 8];
    const uint s3 = csr_src[j + 12];
    const uint4 r0 = *(const uint4*)&feat[(size_t)s0 * 128 + c0];
    const uint4 r1 = *(const uint4*)&feat[(size_t)s1 * 128 + c0];
    const uint4 r2 = *(const uint4*)&feat[(size_t)s2 * 128 + c0];
    const uint4 r3 = *(const uint4*)&feat[(size_t)s3 * 128 + c0];
    ACC8(r0) ACC8(r1) ACC8(r2) ACC8(r3)
  }
  for (; j < e; j += 4) {
    const uint s0 = csr_src[j];
    const uint4 r0 = *(const uint4*)&feat[(size_t)s0 * 128 + c0];
    ACC8(r0)
  }
#undef ACC8
#pragma unroll
  for (int k = 0; k < 8; ++k) {
    acc[k] += __shfl_xor(acc[k], 16, 64);
    acc[k] += __shfl_xor(acc[k], 32, 64);
  }
  if (slot == 0) {
    const float rd = 1.0f / fmaxf((float)(e - s), 1.0f);
    if (MODE == 0) {
      uint4 o;
      o.x = pack2(acc[0] * rd, acc[1] * rd);
      o.y = pack2(acc[2] * rd, acc[3] * rd);
      o.z = pack2(acc[4] * rd, acc[5] * rd);
      o.w = pack2(acc[6] * rd, acc[7] * rd);
      *(uint4*)&bout[(size_t)wid * 128 + c0] = o;
    } else {
      uint4 zv = *(const uint4*)&zb[(size_t)wid * 128 + c0];
      uint4 o;
      o.x = pack2(bfl(zv.x) + acc[0] * rd, bfh(zv.x) + acc[1] * rd);
      o.y = pack2(bfl(zv.y) + acc[2] * rd, bfh(zv.y) + acc[3] * rd);
      o.z = pack2(bfl(zv.z) + acc[4] * rd, bfh(zv.z) + acc[5] * rd);
      o.w = pack2(bfl(zv.w) + acc[6] * rd, bfh(zv.w) + acc[7] * rd);
      *(uint4*)&zb[(size_t)wid * 128 + c0] = o;
    }
  }
}

// ---------------------------------------------------------------------------
// Fused MLP chain (R14 measured-best structure):
//   phase 1: h = relu([aggb|xb] @ WT1 + bl1) -> swizzled LDS Ht
//   phase 2: [p | zb] = h @ WT2 (+bl2)       -> global, both bf16
// Single-buffered As/Bs staging (52KB -> 3 blocks/CU); source-XOR swizzle
// on As/Bs (rule #21), Ht swizzled byte ^= (row&7)<<4.
// ---------------------------------------------------------------------------
__global__ __launch_bounds__(256) void gemm_fused(const ushort* __restrict__ aggb,
                                                  const ushort* __restrict__ xb,
                                                  const ushort* __restrict__ WT1,
                                                  const ushort* __restrict__ WT2,
                                                  const float* __restrict__ bl1,
                                                  const float* __restrict__ bl2,
                                                  ushort* __restrict__ p,
                                                  ushort* __restrict__ zb) {
  __shared__ ushort As[2048];       // 64 rows x 64B   (4 KB)
  __shared__ ushort Bs[8192];       // 256 rows x 64B  (16 KB)
  __shared__ ushort Ht[64 * 256];   // h tile, swizzled (32 KB)
  const int tid = threadIdx.x;
  const int w = tid >> 6;
  const int l = tid & 63;
  const int row0 = blockIdx.x * 64;
  const int wn = w * 64;
  const int fr = l & 15;
  const int kg16 = (l >> 4) * 16;
  const int cr = (l >> 4) * 4;
  const int cc = l & 15;

  const int arow = tid >> 2;
  const int akb = (tid & 3) * 16;
  const int akbs = akb ^ (((arow >> 1) & 3) << 4);
  int agr = row0 + arow;
  agr = (agr < N_NODES) ? agr : (N_NODES - 1);
  const int brow_l = l >> 2;
  const int bkb = (l & 3) * 16;

  // ---- phase 1 ----
  {
    f32x4 acc[4][4] = {};
    for (int kc = 0; kc < 8; ++kc) {
      const ushort* Ab = (kc < 4) ? aggb : xb;
      __syncthreads();
      async_copy16((const char*)Ab + (size_t)agr * 256 + (kc & 3) * 64 + akbs,
                   (char*)As + w * 1024);
#pragma unroll
      for (int i_ = 0; i_ < 4; ++i_) {
        const int c_ = w * 4 + i_;
        const int n_ = c_ * 16 + brow_l;
        const int kbs_ = bkb ^ (((n_ >> 1) & 3) << 4);
        async_copy16((const char*)WT1 + (size_t)n_ * 512 + kc * 64 + kbs_,
                     (char*)Bs + c_ * 1024);
      }
      __syncthreads();
      bf16x8 af[4], bfr[4];
#pragma unroll
      for (int i = 0; i < 4; ++i) {
        const int ra = i * 16 + fr;
        const int ba = ra * 64 + (kg16 ^ (((ra >> 1) & 3) << 4));
        af[i] = *(const bf16x8*)((const char*)As + ba);
      }
#pragma unroll
      for (int j = 0; j < 4; ++j) {
        const int nb = wn + j * 16 + fr;
        const int bb = nb * 64 + (kg16 ^ (((nb >> 1) & 3) << 4));
        bfr[j] = *(const bf16x8*)((const char*)Bs + bb);
      }
#pragma unroll
      for (int i = 0; i < 4; ++i)
#pragma unroll
        for (int j = 0; j < 4; ++j)
          acc[i][j] = __builtin_amdgcn_mfma_f32_16x16x32_bf16(af[i], bfr[j],
                                                              acc[i][j], 0, 0, 0);
    }
#pragma unroll
    for (int i = 0; i < 4; ++i) {
#pragma unroll
      for (int j = 0; j < 4; ++j) {
        const int col = wn + j * 16 + cc;
        const float bv = bl1[col];
#pragma unroll
        for (int r = 0; r < 4; ++r) {
          const int row = i * 16 + cr + r;
          const float v = fmaxf(acc[i][j][r] + bv, 0.f);
          const int ba = (row * 512 + col * 2) ^ ((row & 7) << 4);
          *(ushort*)((char*)Ht + ba) = f2bf(v);
        }
      }
    }
  }
  __syncthreads();

  // ---- phase 2 ----
  f32x4 acc2[4][4] = {};
#pragma unroll
  for (int kc = 0; kc < 8; ++kc) {
    bf16x8 af[4], bfr[4];
#pragma unroll
    for (int i = 0; i < 4; ++i) {
      const int row = i * 16 + fr;
      const int ba = (row * 512 + kc * 64 + kg16) ^ ((row & 7) << 4);
      af[i] = *(const bf16x8*)((const char*)Ht + ba);
    }
#pragma unroll
    for (int j = 0; j < 4; ++j) {
      const int n = wn + j * 16 + fr;
      bfr[j] = *(const bf16x8*)((const char*)WT2 + (size_t)n * 512 + kc * 64 +
                                kg16);
    }
#pragma unroll
    for (int i = 0; i < 4; ++i)
#pragma unroll
      for (int j = 0; j < 4; ++j)
        acc2[i][j] = __builtin_amdgcn_mfma_f32_16x16x32_bf16(af[i], bfr[j],
                                                             acc2[i][j], 0, 0, 0);
  }
#pragma unroll
  for (int i = 0; i < 4; ++i) {
#pragma unroll
    for (int j = 0; j < 4; ++j) {
      const int col = wn + j * 16 + cc;
      const int gcl = col & 127;
      const bool is_p = (col < 128);
      const float bv = is_p ? 0.f : bl2[gcl];
      ushort* dst = is_p ? p : zb;
#pragma unroll
      for (int r = 0; r < 4; ++r) {
        const int grow = row0 + i * 16 + cr + r;
        if (grow < N_NODES) {
          dst[(size_t)grow * 128 + gcl] = f2bf(acc2[i][j][r] + bv);
        }
      }
    }
  }
}

// ---------------------------------------------------------------------------
// Decode: 16 lanes/edge x 16B (8 bf16); 4 edge-slots per wave.
// ---------------------------------------------------------------------------
__global__ __launch_bounds__(256) void dot_kernel(const int* __restrict__ ls,
                                                  const int* __restrict__ ld,
                                                  const ushort* __restrict__ zb,
                                                  float* __restrict__ out) {
  long long tid = (long long)blockIdx.x * 256 + threadIdx.x;
  int e = (int)(tid >> 4);
  int lane = (int)(tid & 15);
  if (e >= N_LABEL) return;
  int a = ls[e], b = ld[e];
  const uint4 va = *(const uint4*)&zb[(size_t)a * 128 + lane * 8];
  const uint4 vb = *(const uint4*)&zb[(size_t)b * 128 + lane * 8];
  float s = bfl(va.x) * bfl(vb.x) + bfh(va.x) * bfh(vb.x) +
            bfl(va.y) * bfl(vb.y) + bfh(va.y) * bfh(vb.y) +
            bfl(va.z) * bfl(vb.z) + bfh(va.z) * bfh(vb.z) +
            bfl(va.w) * bfl(vb.w) + bfh(va.w) * bfh(vb.w);
  s += __shfl_xor(s, 1, 16);
  s += __shfl_xor(s, 2, 16);
  s += __shfl_xor(s, 4, 16);
  s += __shfl_xor(s, 8, 16);
  if (lane == 0) out[e] = s;
}

extern "C" void kernel_launch(void* const* d_in, const int* in_sizes, int n_in,
                              void* d_out, int out_size, void* d_ws, size_t ws_size,
                              hipStream_t stream) {
  const float* x = (const float*)d_in[0];
  const int* ei = (const int*)d_in[1];
  const int* eli = (const int*)d_in[2];
  const float* Wl1 = (const float*)d_in[3];
  const float* bl1 = (const float*)d_in[4];
  const float* Wr1 = (const float*)d_in[5];
  const float* Wl2 = (const float*)d_in[6];
  const float* bl2 = (const float*)d_in[7];
  const float* Wr2 = (const float*)d_in[8];
  float* out = (float*)d_out;

  const int* e_src = ei;
  const int* e_dst = ei + N_EDGES;
  const int* l_src = eli;
  const int* l_dst = eli + N_LABEL;

  char* ws = (char*)d_ws;
  ushort* xb = (ushort*)(ws + 0);           //  25.6 MB
  ushort* aggb = (ushort*)(ws + 25600000);  //  25.6 MB
  ushort* p = (ushort*)(ws + 102400000);    //  25.6 MB
  ushort* zb = (ushort*)(ws + 128000000);   //  25.6 MB (bf16 z)
  ushort* WT1 = (ushort*)(ws + 179200000);  // 128 KB
  ushort* WT2 = (ushort*)(ws + 179331072);  // 128 KB
  uint* tmp = (uint*)(ws + 179462144);      // 6.4 MB packed edges -> csr_src
  int* cnt = (int*)(ws + 185862144);        // (FLEN+1) ints
  int* bsum = (int*)(ws + 186270000);       // 128 ints
  int* row_start = (int*)(ws + 186280000);  // (N_NODES+1) ints

  // --- fused prep: bucket histogram + weight transpose + x cast ---
  prep_kernel<<<NBF + 256 + CAST_NB, 256, 0, stream>>>(
      e_dst, cnt, Wl1, Wr1, Wl2, Wr2, WT1, WT2, x, xb);
  // --- scan of cnt ---
  scan_sums<<<SBLK, 256, 0, stream>>>(cnt, bsum);
  scan_apply<<<SBLK, 256, 0, stream>>>(cnt, bsum);
  // --- deterministic bucket scatter + per-bucket CSR finalize ---
  bucket_fill<<<NBF, 256, 0, stream>>>(e_src, e_dst, cnt, tmp);
  csr_build<<<NBUCK, 256, 0, stream>>>(cnt, tmp, row_start);

  // --- layer 1 aggregation ---
  gather_mean_b<0><<<(N_NODES + 3) / 4, 256, 0, stream>>>(row_start, tmp, xb,
                                                          aggb, nullptr);
  // --- fused MLP chain: h (LDS-only) -> p, zb ---
  gemm_fused<<<(N_NODES + 63) / 64, 256, 0, stream>>>(aggb, xb, WT1, WT2, bl1,
                                                      bl2, p, zb);
  // --- layer 2 aggregation: zb += mean(p[neighbors]) ---
  gather_mean_b<1><<<(N_NODES + 3) / 4, 256, 0, stream>>>(row_start, tmp, p,
                                                          nullptr, zb);

  // --- decode ---
  dot_kernel<<<(int)(((long long)N_LABEL * 16 + 255) / 256), 256, 0, stream>>>(
      l_src, l_dst, zb, out);
}

// Round 17
// 289.174 us; speedup vs baseline: 1.0935x; 1.0551x over previous
//
#include <hip/hip_runtime.h>

#define N_NODES 100000
#define N_EDGES 1600000
#define N_LABEL 200000
#define C_IN 128
#define C_HID 256
#define C_OUT 128

#define BCHUNK 64                                 // nodes per bucket
#define NBUCK ((N_NODES + BCHUNK - 1) / BCHUNK)   // 1563
#define NBF 64                                    // multisplit blocks
#define EPB (N_EDGES / NBF)                       // 25000 edges per block
#define FLEN (NBUCK * NBF)                        // 100032
#define ESTORE 2048                               // max edges per bucket
#define CAST_NB ((N_NODES * C_IN) / (256 * 8))    // 6250
#define SBLK ((FLEN + 1023) / 1024)               // 98

typedef __attribute__((ext_vector_type(8))) short bf16x8;
typedef __attribute__((ext_vector_type(4))) float f32x4;

__device__ __forceinline__ ushort f2bf(float f) {  // RTNE
  uint u = __float_as_uint(f);
  return (ushort)((u + 0x7fffu + ((u >> 16) & 1u)) >> 16);
}

__device__ __forceinline__ uint pack2(float lo, float hi) {
  return (uint)f2bf(lo) | ((uint)f2bf(hi) << 16);
}

__device__ __forceinline__ float bfl(uint u) { return __uint_as_float(u << 16); }
__device__ __forceinline__ float bfh(uint u) {
  return __uint_as_float(u & 0xffff0000u);
}

__device__ __forceinline__ void async_copy16(const void* g, void* lds) {
  __builtin_amdgcn_global_load_lds((const __attribute__((address_space(1))) void*)g,
                                   (__attribute__((address_space(3))) void*)lds,
                                   16, 0, 0);
}

// ---------------------------------------------------------------------------
// Fused prep: blocks [0,64) = bucket histogram; [64,320) = weight transpose;
// [320, 320+6250) = x -> bf16 cast.
// ---------------------------------------------------------------------------
__global__ __launch_bounds__(256) void prep_kernel(const int* __restrict__ dst,
                                                   int* __restrict__ cnt,
                                                   const float* __restrict__ Wl1,
                                                   const float* __restrict__ Wr1,
                                                   const float* __restrict__ Wl2,
                                                   const float* __restrict__ Wr2,
                                                   ushort* __restrict__ WT1,
                                                   ushort* __restrict__ WT2,
                                                   const float* __restrict__ x,
                                                   ushort* __restrict__ xb) {
  __shared__ int lcnt[NBUCK];
  const int blk = blockIdx.x;
  const int t = threadIdx.x;
  if (blk < NBF) {  // --- bucket_count ---
    const int base = blk * EPB;
    for (int b = t; b < NBUCK; b += 256) lcnt[b] = 0;
    __syncthreads();
    for (int i = t; i < EPB; i += 256) {
      atomicAdd(&lcnt[dst[base + i] >> 6], 1);
    }
    __syncthreads();
    for (int b = t; b < NBUCK; b += 256) cnt[b * NBF + blk] = lcnt[b];
  } else if (blk < NBF + 256) {  // --- prep_wt ---
    const int n = blk - NBF;
    const int k = t;
    const float v1 = (k < 128) ? Wl1[k * 256 + n] : Wr1[(k - 128) * 256 + n];
    WT1[n * 256 + k] = f2bf(v1);
    const float v2 = (n < 128) ? Wl2[k * 128 + n] : Wr2[k * 128 + (n - 128)];
    WT2[n * 256 + k] = f2bf(v2);
  } else {  // --- cast_bf16 ---
    const size_t i = ((size_t)(blk - NBF - 256) * 256 + t) * 8;
    const float4 a = *(const float4*)&x[i];
    const float4 b = *(const float4*)&x[i + 4];
    uint4 o;
    o.x = pack2(a.x, a.y);
    o.y = pack2(a.z, a.w);
    o.z = pack2(b.x, b.y);
    o.w = pack2(b.z, b.w);
    *(uint4*)&xb[i] = o;
  }
}

// ---------------------------------------------------------------------------
// Scan phase 1: per-block sums of cnt (1024 elems / block).
// ---------------------------------------------------------------------------
__global__ __launch_bounds__(256) void scan_sums(const int* __restrict__ a,
                                                 int* __restrict__ bsum) {
  __shared__ int red[256];
  const int t = threadIdx.x;
  const int idx = blockIdx.x * 1024 + t * 4;
  int s = 0;
  if (idx + 3 < FLEN) {
    const int4 v = *(const int4*)&a[idx];
    s = v.x + v.y + v.z + v.w;
  } else {
    for (int j = 0; j < 4 && idx + j < FLEN; ++j) s += a[idx + j];
  }
  red[t] = s;
  __syncthreads();
  for (int off = 128; off > 0; off >>= 1) {
    if (t < off) red[t] += red[t + off];
    __syncthreads();
  }
  if (t == 0) bsum[blockIdx.x] = red[0];
}

// ---------------------------------------------------------------------------
// Scan phase 2 (fused tops): each block redundantly scans the 98 block sums.
// ---------------------------------------------------------------------------
__global__ __launch_bounds__(256) void scan_apply(int* __restrict__ a,
                                                  const int* __restrict__ bsum) {
  __shared__ int sh[256];
  __shared__ int bsc[128];
  const int t = threadIdx.x;
  if (t < 128) bsc[t] = (t < SBLK) ? bsum[t] : 0;
  __syncthreads();
  for (int off = 1; off < 128; off <<= 1) {
    int v = 0;
    if (t < 128 && t >= off) v = bsc[t - off];
    __syncthreads();
    if (t < 128 && t >= off) bsc[t] += v;
    __syncthreads();
  }
  const int bbase = (blockIdx.x == 0) ? 0 : bsc[blockIdx.x - 1];
  if (blockIdx.x == SBLK - 1 && t == 0) a[FLEN] = bsc[SBLK - 1];

  const int idx = blockIdx.x * 1024 + t * 4;
  int4 v = make_int4(0, 0, 0, 0);
  const bool full = (idx + 3 < FLEN);
  if (full) {
    v = *(const int4*)&a[idx];
  } else {
    if (idx + 0 < FLEN) v.x = a[idx + 0];
    if (idx + 1 < FLEN) v.y = a[idx + 1];
    if (idx + 2 < FLEN) v.z = a[idx + 2];
    if (idx + 3 < FLEN) v.w = a[idx + 3];
  }
  sh[t] = v.x + v.y + v.z + v.w;
  __syncthreads();
  for (int off = 1; off < 256; off <<= 1) {
    int u = 0;
    if (t >= off) u = sh[t - off];
    __syncthreads();
    if (t >= off) sh[t] += u;
    __syncthreads();
  }
  const int base = bbase + ((t == 0) ? 0 : sh[t - 1]);
  int4 e;
  e.x = base;
  e.y = base + v.x;
  e.z = base + v.x + v.y;
  e.w = base + v.x + v.y + v.z;
  if (full) {
    *(int4*)&a[idx] = e;
  } else {
    if (idx + 0 < FLEN) a[idx + 0] = e.x;
    if (idx + 1 < FLEN) a[idx + 1] = e.y;
    if (idx + 2 < FLEN) a[idx + 2] = e.z;
    if (idx + 3 < FLEN) a[idx + 3] = e.w;
  }
}

// ---------------------------------------------------------------------------
// Multisplit P3: deterministic bucket scatter with LDS cursors.
// ---------------------------------------------------------------------------
__global__ __launch_bounds__(256) void bucket_fill(const int* __restrict__ src,
                                                   const int* __restrict__ dst,
                                                   const int* __restrict__ cnt,
                                                   uint* __restrict__ tmp) {
  __shared__ int lcur[NBUCK];
  const int t = threadIdx.x;
  const int base = blockIdx.x * EPB;
  for (int b = t; b < NBUCK; b += 256) lcur[b] = cnt[b * NBF + blockIdx.x];
  __syncthreads();
  for (int i = t; i < EPB; i += 256) {
    const int d = dst[base + i];
    const int s = src[base + i];
    const int pos = atomicAdd(&lcur[d >> 6], 1);
    tmp[pos] = ((uint)s << 6) | (uint)(d & 63);
  }
}

// ---------------------------------------------------------------------------
// Per-bucket CSR finalize, in LDS; tmp becomes csr_src in place.
// ---------------------------------------------------------------------------
__global__ __launch_bounds__(256) void csr_build(const int* __restrict__ cnt,
                                                 uint* __restrict__ tmp,
                                                 int* __restrict__ row_start) {
  __shared__ uint est[ESTORE];
  __shared__ uint eso[ESTORE];
  __shared__ int lcnt[BCHUNK];
  __shared__ int lcur[BCHUNK];
  const int b = blockIdx.x;
  const int t = threadIdx.x;
  const int s = cnt[b * NBF];
  const int e = cnt[(b + 1) * NBF];
  const int n = e - s;
  for (int j = t; j < n; j += 256) est[j] = tmp[s + j];
  if (t < BCHUNK) lcnt[t] = 0;
  __syncthreads();
  for (int j = t; j < n; j += 256) atomicAdd(&lcnt[est[j] & 63], 1);
  __syncthreads();
  for (int off = 1; off < BCHUNK; off <<= 1) {
    int v = 0;
    if (t >= off && t < BCHUNK) v = lcnt[t - off];
    __syncthreads();
    if (t >= off && t < BCHUNK) lcnt[t] += v;
    __syncthreads();
  }
  if (t < BCHUNK) {
    const int ex = (t == 0) ? 0 : lcnt[t - 1];
    lcur[t] = ex;
    const int node = b * BCHUNK + t;
    if (node < N_NODES) row_start[node] = s + ex;
  }
  if (b == NBUCK - 1 && t == 0) row_start[N_NODES] = e;
  __syncthreads();
  for (int j = t; j < n; j += 256) {
    const uint v = est[j];
    const int pos = atomicAdd(&lcur[v & 63], 1);
    eso[pos] = v >> 6;
  }
  __syncthreads();
  for (int j = t; j < n; j += 256) tmp[s + j] = eso[j];
}

// ---------------------------------------------------------------------------
// Mean aggregation: one wave per node; 4 edge-slots x 16 lanes x 16B.
// MODE 0: write bf16 mean.  MODE 1: zb[node] += mean (bf16 RMW, slot 0).
// ---------------------------------------------------------------------------
template <int MODE>
__global__ __launch_bounds__(256) void gather_mean_b(const int* __restrict__ row_start,
                                                     const uint* __restrict__ csr_src,
                                                     const ushort* __restrict__ feat,
                                                     ushort* __restrict__ bout,
                                                     ushort* __restrict__ zb) {
  const int wid = blockIdx.x * 4 + (threadIdx.x >> 6);
  const int lane = threadIdx.x & 63;
  if (wid >= N_NODES) return;
  const int s = row_start[wid];
  const int e = row_start[wid + 1];
  const int slot = lane >> 4;
  const int c0 = (lane & 15) * 8;
  float acc[8] = {};
  int j = s + slot;
#define ACC8(r)                                   \
  acc[0] += bfl(r.x); acc[1] += bfh(r.x);         \
  acc[2] += bfl(r.y); acc[3] += bfh(r.y);         \
  acc[4] += bfl(r.z); acc[5] += bfh(r.z);         \
  acc[6] += bfl(r.w); acc[7] += bfh(r.w);
  for (; j + 12 < e; j += 16) {
    const uint s0 = csr_src[j];
    const uint s1 = csr_src[j + 4];
    const uint s2 = csr_src[j + 8];
    const uint s3 = csr_src[j + 12];
    const uint4 r0 = *(const uint4*)&feat[(size_t)s0 * 128 + c0];
    const uint4 r1 = *(const uint4*)&feat[(size_t)s1 * 128 + c0];
    const uint4 r2 = *(const uint4*)&feat[(size_t)s2 * 128 + c0];
    const uint4 r3 = *(const uint4*)&feat[(size_t)s3 * 128 + c0];
    ACC8(r0) ACC8(r1) ACC8(r2) ACC8(r3)
  }
  for (; j < e; j += 4) {
    const uint s0 = csr_src[j];
    const uint4 r0 = *(const uint4*)&feat[(size_t)s0 * 128 + c0];
    ACC8(r0)
  }
#undef ACC8
#pragma unroll
  for (int k = 0; k < 8; ++k) {
    acc[k] += __shfl_xor(acc[k], 16, 64);
    acc[k] += __shfl_xor(acc[k], 32, 64);
  }
  if (slot == 0) {
    const float rd = 1.0f / fmaxf((float)(e - s), 1.0f);
    if (MODE == 0) {
      uint4 o;
      o.x = pack2(acc[0] * rd, acc[1] * rd);
      o.y = pack2(acc[2] * rd, acc[3] * rd);
      o.z = pack2(acc[4] * rd, acc[5] * rd);
      o.w = pack2(acc[6] * rd, acc[7] * rd);
      *(uint4*)&bout[(size_t)wid * 128 + c0] = o;
    } else {
      uint4 zv = *(const uint4*)&zb[(size_t)wid * 128 + c0];
      uint4 o;
      o.x = pack2(bfl(zv.x) + acc[0] * rd, bfh(zv.x) + acc[1] * rd);
      o.y = pack2(bfl(zv.y) + acc[2] * rd, bfh(zv.y) + acc[3] * rd);
      o.z = pack2(bfl(zv.z) + acc[4] * rd, bfh(zv.z) + acc[5] * rd);
      o.w = pack2(bfl(zv.w) + acc[6] * rd, bfh(zv.w) + acc[7] * rd);
      *(uint4*)&zb[(size_t)wid * 128 + c0] = o;
    }
  }
}

// ---------------------------------------------------------------------------
// Fused MLP chain, 8-wave variant (512 threads, same 52KB LDS, same tile):
//   phase 1: h = relu([aggb|xb] @ WT1 + bl1) -> swizzled LDS Ht
//   phase 2: [p | zb] = h @ WT2 (+bl2)       -> global, both bf16
// Each wave owns a 32-col slice (acc 4x2). 3 blocks/CU x 8 waves = 24
// waves/CU (vs 12) -> cross-block wave overlap hides the per-kc barrier
// drains (m114 mechanism). Staging remapped for 512 threads; swizzles
// unchanged (rule #21 source-XOR on As/Bs, Ht byte ^= (row&7)<<4).
// ---------------------------------------------------------------------------
__global__ __launch_bounds__(512) void gemm_fused(const ushort* __restrict__ aggb,
                                                  const ushort* __restrict__ xb,
                                                  const ushort* __restrict__ WT1,
                                                  const ushort* __restrict__ WT2,
                                                  const float* __restrict__ bl1,
                                                  const float* __restrict__ bl2,
                                                  ushort* __restrict__ p,
                                                  ushort* __restrict__ zb) {
  __shared__ ushort As[2048];       // 64 rows x 64B   (4 KB)
  __shared__ ushort Bs[8192];       // 256 rows x 64B  (16 KB)
  __shared__ ushort Ht[64 * 256];   // h tile, swizzled (32 KB)
  const int tid = threadIdx.x;
  const int w = tid >> 6;           // 0..7
  const int l = tid & 63;
  const int row0 = blockIdx.x * 64;
  const int wn = w * 32;            // wave's 32-col slice
  const int fr = l & 15;
  const int kg16 = (l >> 4) * 16;
  const int cr = (l >> 4) * 4;
  const int cc = l & 15;

  // A staging (tid < 256): 64 rows x 64B, source-XOR swizzled
  const int arow = (tid & 255) >> 2;
  const int akb = (tid & 3) * 16;
  const int akbs = akb ^ (((arow >> 1) & 3) << 4);
  int agr = row0 + arow;
  agr = (agr < N_NODES) ? agr : (N_NODES - 1);
  // B staging (all 512 threads, 2 chunks): row n_ = c*128 + (tid>>2)
  const int brow_half = tid >> 2;   // 0..127
  const int bkb = (tid & 3) * 16;

  // ---- phase 1 ----
  {
    f32x4 acc[4][2] = {};
    for (int kc = 0; kc < 8; ++kc) {
      const ushort* Ab = (kc < 4) ? aggb : xb;
      __syncthreads();
      if (tid < 256) {
        async_copy16((const char*)Ab + (size_t)agr * 256 + (kc & 3) * 64 + akbs,
                     (char*)As + (w & 3) * 1024);
      }
#pragma unroll
      for (int c_ = 0; c_ < 2; ++c_) {
        const int n_ = c_ * 128 + brow_half;
        const int kbs_ = bkb ^ (((n_ >> 1) & 3) << 4);
        async_copy16((const char*)WT1 + (size_t)n_ * 512 + kc * 64 + kbs_,
                     (char*)Bs + c_ * 8192 + w * 1024);
      }
      __syncthreads();
      bf16x8 af[4], bfr[2];
#pragma unroll
      for (int i = 0; i < 4; ++i) {
        const int ra = i * 16 + fr;
        const int ba = ra * 64 + (kg16 ^ (((ra >> 1) & 3) << 4));
        af[i] = *(const bf16x8*)((const char*)As + ba);
      }
#pragma unroll
      for (int j = 0; j < 2; ++j) {
        const int nb = wn + j * 16 + fr;
        const int bb = nb * 64 + (kg16 ^ (((nb >> 1) & 3) << 4));
        bfr[j] = *(const bf16x8*)((const char*)Bs + bb);
      }
#pragma unroll
      for (int i = 0; i < 4; ++i)
#pragma unroll
        for (int j = 0; j < 2; ++j)
          acc[i][j] = __builtin_amdgcn_mfma_f32_16x16x32_bf16(af[i], bfr[j],
                                                              acc[i][j], 0, 0, 0);
    }
#pragma unroll
    for (int i = 0; i < 4; ++i) {
#pragma unroll
      for (int j = 0; j < 2; ++j) {
        const int col = wn + j * 16 + cc;
        const float bv = bl1[col];
#pragma unroll
        for (int r = 0; r < 4; ++r) {
          const int row = i * 16 + cr + r;
          const float v = fmaxf(acc[i][j][r] + bv, 0.f);
          const int ba = (row * 512 + col * 2) ^ ((row & 7) << 4);
          *(ushort*)((char*)Ht + ba) = f2bf(v);
        }
      }
    }
  }
  __syncthreads();

  // ---- phase 2 ----
  f32x4 acc2[4][2] = {};
#pragma unroll
  for (int kc = 0; kc < 8; ++kc) {
    bf16x8 af[4], bfr[2];
#pragma unroll
    for (int i = 0; i < 4; ++i) {
      const int row = i * 16 + fr;
      const int ba = (row * 512 + kc * 64 + kg16) ^ ((row & 7) << 4);
      af[i] = *(const bf16x8*)((const char*)Ht + ba);
    }
#pragma unroll
    for (int j = 0; j < 2; ++j) {
      const int n = wn + j * 16 + fr;
      bfr[j] = *(const bf16x8*)((const char*)WT2 + (size_t)n * 512 + kc * 64 +
                                kg16);
    }
#pragma unroll
    for (int i = 0; i < 4; ++i)
#pragma unroll
      for (int j = 0; j < 2; ++j)
        acc2[i][j] = __builtin_amdgcn_mfma_f32_16x16x32_bf16(af[i], bfr[j],
                                                             acc2[i][j], 0, 0, 0);
  }
#pragma unroll
  for (int i = 0; i < 4; ++i) {
#pragma unroll
    for (int j = 0; j < 2; ++j) {
      const int col = wn + j * 16 + cc;  // 0..255; <128 -> p, >=128 -> zb
      const int gcl = col & 127;
      const bool is_p = (col < 128);
      const float bv = is_p ? 0.f : bl2[gcl];
      ushort* dst = is_p ? p : zb;
#pragma unroll
      for (int r = 0; r < 4; ++r) {
        const int grow = row0 + i * 16 + cr + r;
        if (grow < N_NODES) {
          dst[(size_t)grow * 128 + gcl] = f2bf(acc2[i][j][r] + bv);
        }
      }
    }
  }
}

// ---------------------------------------------------------------------------
// Decode: 16 lanes/edge x 16B (8 bf16); 4 edge-slots per wave.
// ---------------------------------------------------------------------------
__global__ __launch_bounds__(256) void dot_kernel(const int* __restrict__ ls,
                                                  const int* __restrict__ ld,
                                                  const ushort* __restrict__ zb,
                                                  float* __restrict__ out) {
  long long tid = (long long)blockIdx.x * 256 + threadIdx.x;
  int e = (int)(tid >> 4);
  int lane = (int)(tid & 15);
  if (e >= N_LABEL) return;
  int a = ls[e], b = ld[e];
  const uint4 va = *(const uint4*)&zb[(size_t)a * 128 + lane * 8];
  const uint4 vb = *(const uint4*)&zb[(size_t)b * 128 + lane * 8];
  float s = bfl(va.x) * bfl(vb.x) + bfh(va.x) * bfh(vb.x) +
            bfl(va.y) * bfl(vb.y) + bfh(va.y) * bfh(vb.y) +
            bfl(va.z) * bfl(vb.z) + bfh(va.z) * bfh(vb.z) +
            bfl(va.w) * bfl(vb.w) + bfh(va.w) * bfh(vb.w);
  s += __shfl_xor(s, 1, 16);
  s += __shfl_xor(s, 2, 16);
  s += __shfl_xor(s, 4, 16);
  s += __shfl_xor(s, 8, 16);
  if (lane == 0) out[e] = s;
}

extern "C" void kernel_launch(void* const* d_in, const int* in_sizes, int n_in,
                              void* d_out, int out_size, void* d_ws, size_t ws_size,
                              hipStream_t stream) {
  const float* x = (const float*)d_in[0];
  const int* ei = (const int*)d_in[1];
  const int* eli = (const int*)d_in[2];
  const float* Wl1 = (const float*)d_in[3];
  const float* bl1 = (const float*)d_in[4];
  const float* Wr1 = (const float*)d_in[5];
  const float* Wl2 = (const float*)d_in[6];
  const float* bl2 = (const float*)d_in[7];
  const float* Wr2 = (const float*)d_in[8];
  float* out = (float*)d_out;

  const int* e_src = ei;
  const int* e_dst = ei + N_EDGES;
  const int* l_src = eli;
  const int* l_dst = eli + N_LABEL;

  char* ws = (char*)d_ws;
  ushort* xb = (ushort*)(ws + 0);           //  25.6 MB
  ushort* aggb = (ushort*)(ws + 25600000);  //  25.6 MB
  ushort* p = (ushort*)(ws + 102400000);    //  25.6 MB
  ushort* zb = (ushort*)(ws + 128000000);   //  25.6 MB (bf16 z)
  ushort* WT1 = (ushort*)(ws + 179200000);  // 128 KB
  ushort* WT2 = (ushort*)(ws + 179331072);  // 128 KB
  uint* tmp = (uint*)(ws + 179462144);      // 6.4 MB packed edges -> csr_src
  int* cnt = (int*)(ws + 185862144);        // (FLEN+1) ints
  int* bsum = (int*)(ws + 186270000);       // 128 ints
  int* row_start = (int*)(ws + 186280000);  // (N_NODES+1) ints

  // --- fused prep: bucket histogram + weight transpose + x cast ---
  prep_kernel<<<NBF + 256 + CAST_NB, 256, 0, stream>>>(
      e_dst, cnt, Wl1, Wr1, Wl2, Wr2, WT1, WT2, x, xb);
  // --- scan of cnt ---
  scan_sums<<<SBLK, 256, 0, stream>>>(cnt, bsum);
  scan_apply<<<SBLK, 256, 0, stream>>>(cnt, bsum);
  // --- deterministic bucket scatter + per-bucket CSR finalize ---
  bucket_fill<<<NBF, 256, 0, stream>>>(e_src, e_dst, cnt, tmp);
  csr_build<<<NBUCK, 256, 0, stream>>>(cnt, tmp, row_start);

  // --- layer 1 aggregation ---
  gather_mean_b<0><<<(N_NODES + 3) / 4, 256, 0, stream>>>(row_start, tmp, xb,
                                                          aggb, nullptr);
  // --- fused MLP chain: h (LDS-only) -> p, zb ---
  gemm_fused<<<(N_NODES + 63) / 64, 512, 0, stream>>>(aggb, xb, WT1, WT2, bl1,
                                                      bl2, p, zb);
  // --- layer 2 aggregation: zb += mean(p[neighbors]) ---
  gather_mean_b<1><<<(N_NODES + 3) / 4, 256, 0, stream>>>(row_start, tmp, p,
                                                          nullptr, zb);

  // --- decode ---
  dot_kernel<<<(int)(((long long)N_LABEL * 16 + 255) / 256), 256, 0, stream>>>(
      l_src, l_dst, zb, out);
}